// Round 4
// baseline (546.517 us; speedup 1.0000x reference)
//
#include <hip/hip_runtime.h>
#include <math.h>

typedef unsigned short ushort_t;
typedef unsigned int uint_t;
typedef short short8 __attribute__((ext_vector_type(8)));
typedef short short4a __attribute__((ext_vector_type(4)));
typedef float float4a __attribute__((ext_vector_type(4)));

#define B_SZ 4
#define S_SZ 2048
#define E_SZ 1024
#define H_SZ 16
#define HD_SZ 64

// ---- helpers ----
__device__ __forceinline__ float bf2f(ushort_t u) {
    uint_t v = ((uint_t)u) << 16;
    return __builtin_bit_cast(float, v);
}
__device__ __forceinline__ ushort_t f2bf(float f) {
    uint_t u = __builtin_bit_cast(uint_t, f);
    u = (u + 0x7fff + ((u >> 16) & 1)) >> 16;
    return (ushort_t)u;
}
__device__ __forceinline__ void async_copy16(const void* g, void* l) {
    __builtin_amdgcn_global_load_lds(
        (const __attribute__((address_space(1))) void*)g,
        (__attribute__((address_space(3))) void*)l, 16, 0, 0);
}

// ---- kernel 1: transpose 4 fp32 weight matrices (E x E) -> bf16 ----
__global__ __launch_bounds__(256) void transpose4(
    const float* __restrict__ W0, const float* __restrict__ W1,
    const float* __restrict__ W2, const float* __restrict__ W3,
    ushort_t* __restrict__ out)
{
    const float* src;
    switch (blockIdx.z) {
        case 0: src = W0; break;
        case 1: src = W1; break;
        case 2: src = W2; break;
        default: src = W3; break;
    }
    ushort_t* dst = out + (size_t)blockIdx.z * (E_SZ * E_SZ);
    __shared__ ushort_t t[32][33];
    int x = blockIdx.x * 32 + threadIdx.x;   // src col (n)
    int y0 = blockIdx.y * 32;                // src row base (k)
    for (int i = threadIdx.y; i < 32; i += 8)
        t[i][threadIdx.x] = f2bf(src[(size_t)(y0 + i) * E_SZ + x]);
    __syncthreads();
    int yy = blockIdx.x * 32;                // dst row base (n)
    int xx = y0 + threadIdx.x;               // dst col (k)
    for (int i = threadIdx.y; i < 32; i += 8)
        dst[(size_t)(yy + i) * E_SZ + xx] = t[threadIdx.x][i];
}

// ---- kernel 2: Y[m,n] = sum_k X[m,k] * Wt[n,k] + bias[n] ----
// M=8192, N=K=1024. 128x128 tile, BK=32, 4 waves (2x2 of 64x64).
// XF32: X fp32 (converted to bf16 in VGPRs while staging); else X bf16
// (async global_load_lds path). bias fp32.
// OUTF32: Y is fp32 [M,N] (final output). Else bf16: mode 0 -> [M,N],
// mode 1 -> [B,E,S] transposed (for V).
template<bool XF32, bool OUTF32>
__global__ __launch_bounds__(256) void gemm_bt_bias(
    const void* __restrict__ Xv, const ushort_t* __restrict__ Wt,
    const float* __restrict__ bias, void* __restrict__ Yv, int mode)
{
    __shared__ __align__(16) ushort_t As[4096];  // [g(4)][row(128)][8]
    __shared__ __align__(16) ushort_t Bs[4096];
    const int tid = threadIdx.x;
    const int lane = tid & 63;
    const int quad = lane >> 4;
    const int l15 = lane & 15;
    const int wid = tid >> 6;
    const int tileM = blockIdx.y * 128;
    const int tileN = blockIdx.x * 128;
    const int wm = (wid >> 1) * 64;
    const int wn = (wid & 1) * 64;

    float4a acc[4][4];
    for (int i = 0; i < 4; i++)
        for (int j = 0; j < 4; j++)
            acc[i][j] = (float4a){0.f, 0.f, 0.f, 0.f};

    const int L0 = tid, L1 = tid + 256;
    const int g0 = L0 >> 7, r0 = L0 & 127;
    const int g1 = L1 >> 7, r1 = L1 & 127;
    const ushort_t* Wa0 = Wt + (size_t)(tileN + r0) * E_SZ + g0 * 8;
    const ushort_t* Wa1 = Wt + (size_t)(tileN + r1) * E_SZ + g1 * 8;

    const float* Xf0; const float* Xf1;
    const ushort_t* Xb0; const ushort_t* Xb1;
    if constexpr (XF32) {
        const float* X = (const float*)Xv;
        Xf0 = X + (size_t)(tileM + r0) * E_SZ + g0 * 8;
        Xf1 = X + (size_t)(tileM + r1) * E_SZ + g1 * 8;
    } else {
        const ushort_t* X = (const ushort_t*)Xv;
        Xb0 = X + (size_t)(tileM + r0) * E_SZ + g0 * 8;
        Xb1 = X + (size_t)(tileM + r1) * E_SZ + g1 * 8;
    }

    for (int k0 = 0; k0 < E_SZ; k0 += 32) {
        if constexpr (XF32) {
            float4a u0 = *(const float4a*)(Xf0 + k0);
            float4a u1 = *(const float4a*)(Xf0 + k0 + 4);
            float4a u2 = *(const float4a*)(Xf1 + k0);
            float4a u3 = *(const float4a*)(Xf1 + k0 + 4);
            short8 s0, s1;
            for (int j = 0; j < 4; j++) {
                s0[j]     = (short)f2bf(u0[j]);
                s0[j + 4] = (short)f2bf(u1[j]);
                s1[j]     = (short)f2bf(u2[j]);
                s1[j + 4] = (short)f2bf(u3[j]);
            }
            *(short8*)&As[L0 * 8] = s0;
            *(short8*)&As[L1 * 8] = s1;
        } else {
            async_copy16(Xb0 + k0, &As[L0 * 8]);
            async_copy16(Xb1 + k0, &As[L1 * 8]);
        }
        async_copy16(Wa0 + k0, &Bs[L0 * 8]);
        async_copy16(Wa1 + k0, &Bs[L1 * 8]);
        __syncthreads();
        short8 a[4], b[4];
        for (int mt = 0; mt < 4; mt++)
            a[mt] = *(const short8*)&As[quad * 1024 + (wm + mt * 16 + l15) * 8];
        for (int nt = 0; nt < 4; nt++)
            b[nt] = *(const short8*)&Bs[quad * 1024 + (wn + nt * 16 + l15) * 8];
        for (int mt = 0; mt < 4; mt++)
            for (int nt = 0; nt < 4; nt++)
                acc[mt][nt] = __builtin_amdgcn_mfma_f32_16x16x32_bf16(
                    a[mt], b[nt], acc[mt][nt], 0, 0, 0);
        __syncthreads();
    }

    for (int nt = 0; nt < 4; nt++) {
        int n = tileN + wn + nt * 16 + l15;
        float bv = bias[n];
        for (int mt = 0; mt < 4; mt++) {
            for (int r = 0; r < 4; r++) {
                int m = tileM + wm + mt * 16 + quad * 4 + r;
                float v = acc[mt][nt][r] + bv;
                if constexpr (OUTF32) {
                    ((float*)Yv)[(size_t)m * E_SZ + n] = v;
                } else {
                    ushort_t* Y = (ushort_t*)Yv;
                    if (mode == 0) {
                        Y[(size_t)m * E_SZ + n] = f2bf(v);
                    } else {
                        int bb = m >> 11, s = m & 2047;
                        Y[((size_t)(bb * E_SZ + n)) * S_SZ + s] = f2bf(v);
                    }
                }
            }
        }
    }
}

// ---- kernel 3: flash attention (all operands bf16, ws-resident) ----
// Q,K in [B,S,E] (per head: rows s, cols d). V in [B,E,S] (transposed).
// Block: 128 q rows for one (b,h). 4 waves, each owns 32 q rows.
// S^T = K.Q^T via 16x16x32 MFMA (C-layout: row=kidx, col=q).
// P^T round-trips through LDS (Ps[q][kidx], bf16) and feeds a second
// 16x16x32 MFMA: O^T = V^T . P^T.
__global__ __launch_bounds__(256) void attn(
    const ushort_t* __restrict__ Q, const ushort_t* __restrict__ K,
    const ushort_t* __restrict__ V, ushort_t* __restrict__ ctx)
{
    // Ps[128][136] (17408) aliases Qs[8][128][8] (8192): Qs dead after kt==0.
    __shared__ __align__(16) ushort_t smem[34304];
    ushort_t* PQ = smem;                 // Qs then Ps
    ushort_t* Ks = smem + 17408;         // [g(8)][row(128)][8]
    ushort_t* Vt = smem + 25600;         // [d(64)][kidx pad 136]

    const int tid = threadIdx.x;
    const int lane = tid & 63;
    const int quad = lane >> 4;
    const int l15 = lane & 15;
    const int wid = tid >> 6;
    const int qt = blockIdx.x;              // 0..15
    const int bh = blockIdx.y;              // 0..63
    const int b = bh >> 4, h = bh & 15;
    const int s0 = qt * 128;
    const int wq = wid * 32;

    // stage Q once (completion covered by first in-loop barrier)
    for (int p = 0; p < 4; p++) {
        int L = p * 256 + tid;
        int g = L >> 7, r = L & 127;
        const ushort_t* src = Q + ((size_t)(b * S_SZ + s0 + r)) * E_SZ + h * HD_SZ + g * 8;
        async_copy16(src, &PQ[L * 8]);
    }

    float4a st[8][2];       // S^T acc: mt over kidx(8 x16), nt over q(2 x16)
    float4a o[4][2];        // O^T acc: mt over d(4 x16), nt over q(2 x16)
    for (int mt = 0; mt < 4; mt++)
        for (int nt = 0; nt < 2; nt++)
            o[mt][nt] = (float4a){0.f, 0.f, 0.f, 0.f};
    float mrow[2] = {-1e30f, -1e30f};
    float lrow[2] = {0.f, 0.f};
    short8 qf[2][2];

    for (int kt = 0; kt < 16; kt++) {
        // stage K tile (async, lane-consecutive 16B)
        for (int p = 0; p < 4; p++) {
            int L = p * 256 + tid;
            int g = L >> 7, r = L & 127;
            const ushort_t* src = K + ((size_t)(b * S_SZ + kt * 128 + r)) * E_SZ + h * HD_SZ + g * 8;
            async_copy16(src, &Ks[L * 8]);
        }
        // stage V^T tile (V already [B,E,S]; rows d, contiguous kidx)
        for (int p = 0; p < 4; p++) {
            int c = p * 256 + tid;
            int d = c >> 4, cc = c & 15;
            const ushort_t* src = V + ((size_t)(b * E_SZ + h * HD_SZ + d)) * S_SZ + kt * 128 + cc * 8;
            short8 val = *(const short8*)src;
            *(short8*)&Vt[d * 136 + cc * 8] = val;
        }
        __syncthreads();
        if (kt == 0) {
            for (int ks = 0; ks < 2; ks++)
                for (int nt = 0; nt < 2; nt++)
                    qf[ks][nt] = *(const short8*)&PQ[(ks * 4 + quad) * 1024 + (wq + nt * 16 + l15) * 8];
            __syncthreads();   // Ps writes below alias Qs; wait for all qf loads
        }

        // S^T[kidx][q] = sum_d K[kidx][d] * Q[q][d]
        for (int mt = 0; mt < 8; mt++)
            for (int nt = 0; nt < 2; nt++)
                st[mt][nt] = (float4a){0.f, 0.f, 0.f, 0.f};
        for (int ks = 0; ks < 2; ks++) {
            for (int mt = 0; mt < 8; mt++) {
                short8 kf = *(const short8*)&Ks[(ks * 4 + quad) * 1024 + (mt * 16 + l15) * 8];
                for (int nt = 0; nt < 2; nt++)
                    st[mt][nt] = __builtin_amdgcn_mfma_f32_16x16x32_bf16(
                        kf, qf[ks][nt], st[mt][nt], 0, 0, 0);
            }
        }

        // scale + online softmax (softmax rows = q = cols of S^T = lane&15)
        float rmax[2] = {-1e30f, -1e30f};
        for (int mt = 0; mt < 8; mt++)
            for (int nt = 0; nt < 2; nt++)
                for (int r = 0; r < 4; r++) {
                    float v = st[mt][nt][r] * 0.125f;
                    st[mt][nt][r] = v;
                    rmax[nt] = fmaxf(rmax[nt], v);
                }
        for (int nt = 0; nt < 2; nt++) {
            rmax[nt] = fmaxf(rmax[nt], __shfl_xor(rmax[nt], 16));
            rmax[nt] = fmaxf(rmax[nt], __shfl_xor(rmax[nt], 32));
        }
        float alpha[2], rsum[2] = {0.f, 0.f};
        for (int nt = 0; nt < 2; nt++) {
            float mn = fmaxf(mrow[nt], rmax[nt]);
            alpha[nt] = __expf(mrow[nt] - mn);
            mrow[nt] = mn;
        }
        // exp, accumulate row-sum, write P^T to LDS as Ps[q][kidx] (bf16).
        // Each wave touches only its own q rows -> no barrier needed.
        for (int mt = 0; mt < 8; mt++)
            for (int nt = 0; nt < 2; nt++) {
                short4a pp;
                for (int r = 0; r < 4; r++) {
                    float ev = __expf(st[mt][nt][r] - mrow[nt]);
                    rsum[nt] += ev;
                    pp[r] = (short)f2bf(ev);
                }
                *(short4a*)&PQ[(wq + nt * 16 + l15) * 136 + mt * 16 + quad * 4] = pp;
            }
        for (int nt = 0; nt < 2; nt++) {
            rsum[nt] += __shfl_xor(rsum[nt], 16);
            rsum[nt] += __shfl_xor(rsum[nt], 32);
            lrow[nt] = lrow[nt] * alpha[nt] + rsum[nt];
        }
        for (int mt = 0; mt < 4; mt++)
            for (int nt = 0; nt < 2; nt++)
                for (int r = 0; r < 4; r++)
                    o[mt][nt][r] *= alpha[nt];

        // O^T[d][q] += sum_kidx V^T[d][kidx] * P^T[kidx][q]  (16x16x32)
        for (int kk = 0; kk < 4; kk++) {
            short8 a[4], pb[2];
            for (int mt = 0; mt < 4; mt++)
                a[mt] = *(const short8*)&Vt[(mt * 16 + l15) * 136 + kk * 32 + quad * 8];
            for (int nt = 0; nt < 2; nt++)
                pb[nt] = *(const short8*)&PQ[(wq + nt * 16 + l15) * 136 + kk * 32 + quad * 8];
            for (int mt = 0; mt < 4; mt++)
                for (int nt = 0; nt < 2; nt++)
                    o[mt][nt] = __builtin_amdgcn_mfma_f32_16x16x32_bf16(
                        a[mt], pb[nt], o[mt][nt], 0, 0, 0);
        }
        __syncthreads();
    }

    // epilogue: ctx[b, s, h*64+d] = O^T[d][q] / l[q]
    for (int nt = 0; nt < 2; nt++) {
        float inv = 1.f / lrow[nt];
        int s = s0 + wq + nt * 16 + l15;
        size_t base = ((size_t)(b * S_SZ + s)) * E_SZ + h * HD_SZ;
        for (int mt = 0; mt < 4; mt++)
            for (int r = 0; r < 4; r++) {
                int d = mt * 16 + quad * 4 + r;
                ctx[base + d] = f2bf(o[mt][nt][r] * inv);
            }
    }
}

extern "C" void kernel_launch(void* const* d_in, const int* in_sizes, int n_in,
                              void* d_out, int out_size, void* d_ws, size_t ws_size,
                              hipStream_t stream) {
    // Inputs fp32 per the reference; OUTPUT fp32 per the reference.
    const float* q_in = (const float*)d_in[0];
    const float* k_in = (const float*)d_in[1];
    const float* v_in = (const float*)d_in[2];
    const float* Wq = (const float*)d_in[3];
    const float* bq = (const float*)d_in[4];
    const float* Wk = (const float*)d_in[5];
    const float* bk = (const float*)d_in[6];
    const float* Wv = (const float*)d_in[7];
    const float* bv = (const float*)d_in[8];
    const float* Wo = (const float*)d_in[9];
    const float* bo = (const float*)d_in[10];

    ushort_t* ws = (ushort_t*)d_ws;
    const size_t WMAT = (size_t)E_SZ * E_SZ;           // 1M elements
    const size_t TEN = (size_t)B_SZ * S_SZ * E_SZ;     // 8M elements
    ushort_t* Wt = ws;                 // 4 transposed bf16 weight matrices
    ushort_t* qp = ws + 4 * WMAT;
    ushort_t* kp = qp + TEN;
    ushort_t* vp = kp + TEN;           // stored [B, E, S]
    ushort_t* cx = vp + TEN;

    transpose4<<<dim3(32, 32, 4), dim3(32, 8), 0, stream>>>(Wq, Wk, Wv, Wo, Wt);
    gemm_bt_bias<true, false><<<dim3(8, 64), 256, 0, stream>>>(q_in, Wt, bq, qp, 0);
    gemm_bt_bias<true, false><<<dim3(8, 64), 256, 0, stream>>>(k_in, Wt + WMAT, bk, kp, 0);
    gemm_bt_bias<true, false><<<dim3(8, 64), 256, 0, stream>>>(v_in, Wt + 2 * WMAT, bv, vp, 1);
    attn<<<dim3(16, 64), 256, 0, stream>>>(qp, kp, vp, cx);
    gemm_bt_bias<false, true><<<dim3(8, 64), 256, 0, stream>>>(cx, Wt + 3 * WMAT, bo, d_out, 0);
}

// Round 5
// 531.872 us; speedup vs baseline: 1.0275x; 1.0275x over previous
//
#include <hip/hip_runtime.h>
#include <math.h>

typedef unsigned short ushort_t;
typedef unsigned int uint_t;
typedef short short8 __attribute__((ext_vector_type(8)));
typedef short short4a __attribute__((ext_vector_type(4)));
typedef float float4a __attribute__((ext_vector_type(4)));
typedef uint_t uint4a __attribute__((ext_vector_type(4)));
typedef uint_t uint2a __attribute__((ext_vector_type(2)));

#define B_SZ 4
#define S_SZ 2048
#define E_SZ 1024
#define H_SZ 16
#define HD_SZ 64

#if __has_builtin(__builtin_amdgcn_exp2f)
#define EXP2F(x) __builtin_amdgcn_exp2f(x)
#else
#define EXP2F(x) exp2f(x)
#endif

// ---- helpers ----
__device__ __forceinline__ float bf2f(ushort_t u) {
    uint_t v = ((uint_t)u) << 16;
    return __builtin_bit_cast(float, v);
}
__device__ __forceinline__ ushort_t f2bf(float f) {
    uint_t u = __builtin_bit_cast(uint_t, f);
    u = (u + 0x7fff + ((u >> 16) & 1)) >> 16;
    return (ushort_t)u;
}
// pack 2 fp32 -> 2 bf16 (round half-up) in one v_perm_b32
__device__ __forceinline__ uint_t pk_bf16(float a, float b) {
    uint_t ua = __builtin_bit_cast(uint_t, a) + 0x8000u;
    uint_t ub = __builtin_bit_cast(uint_t, b) + 0x8000u;
#if __has_builtin(__builtin_amdgcn_perm)
    return __builtin_amdgcn_perm(ub, ua, 0x07060302u);
#else
    return (ua >> 16) | (ub & 0xffff0000u);
#endif
}
__device__ __forceinline__ void async_copy16(const void* g, void* l) {
    __builtin_amdgcn_global_load_lds(
        (const __attribute__((address_space(1))) void*)g,
        (__attribute__((address_space(3))) void*)l, 16, 0, 0);
}

// ---- kernel 1: transpose 4 fp32 weight matrices (E x E) -> bf16 ----
__global__ __launch_bounds__(256) void transpose4(
    const float* __restrict__ W0, const float* __restrict__ W1,
    const float* __restrict__ W2, const float* __restrict__ W3,
    ushort_t* __restrict__ out)
{
    const float* src;
    switch (blockIdx.z) {
        case 0: src = W0; break;
        case 1: src = W1; break;
        case 2: src = W2; break;
        default: src = W3; break;
    }
    ushort_t* dst = out + (size_t)blockIdx.z * (E_SZ * E_SZ);
    __shared__ ushort_t t[32][33];
    int x = blockIdx.x * 32 + threadIdx.x;   // src col (n)
    int y0 = blockIdx.y * 32;                // src row base (k)
    for (int i = threadIdx.y; i < 32; i += 8)
        t[i][threadIdx.x] = f2bf(src[(size_t)(y0 + i) * E_SZ + x]);
    __syncthreads();
    int yy = blockIdx.x * 32;                // dst row base (n)
    int xx = y0 + threadIdx.x;               // dst col (k)
    for (int i = threadIdx.y; i < 32; i += 8)
        dst[(size_t)(yy + i) * E_SZ + xx] = t[threadIdx.x][i];
}

// ---- kernel 2: Y[m,n] = sum_k X[m,k] * Wt[n,k] + bias[n] ----
// M=8192, N=K=1024. 128x128 tile, BK=32, 4 waves (2x2 of 64x64).
// XF32: X fp32 (perm-packed to bf16 in VGPRs while staging); else X bf16
// (async global_load_lds path). bias fp32.
// OUTF32: Y fp32 [M,N]. Else bf16: mode 0 -> [M,N], mode 1 -> [B,E,S].
template<bool XF32, bool OUTF32>
__global__ __launch_bounds__(256) void gemm_bt_bias(
    const void* __restrict__ Xv, const ushort_t* __restrict__ Wt,
    const float* __restrict__ bias, void* __restrict__ Yv, int mode)
{
    __shared__ __align__(16) ushort_t As[4096];  // [g(4)][row(128)][8]
    __shared__ __align__(16) ushort_t Bs[4096];
    const int tid = threadIdx.x;
    const int lane = tid & 63;
    const int quad = lane >> 4;
    const int l15 = lane & 15;
    const int wid = tid >> 6;
    const int tileM = blockIdx.y * 128;
    const int tileN = blockIdx.x * 128;
    const int wm = (wid >> 1) * 64;
    const int wn = (wid & 1) * 64;

    float4a acc[4][4];
    for (int i = 0; i < 4; i++)
        for (int j = 0; j < 4; j++)
            acc[i][j] = (float4a){0.f, 0.f, 0.f, 0.f};

    const int L0 = tid, L1 = tid + 256;
    const int g0 = L0 >> 7, r0 = L0 & 127;
    const int g1 = L1 >> 7, r1 = L1 & 127;
    const ushort_t* Wa0 = Wt + (size_t)(tileN + r0) * E_SZ + g0 * 8;
    const ushort_t* Wa1 = Wt + (size_t)(tileN + r1) * E_SZ + g1 * 8;

    const float* Xf0; const float* Xf1;
    const ushort_t* Xb0; const ushort_t* Xb1;
    if constexpr (XF32) {
        const float* X = (const float*)Xv;
        Xf0 = X + (size_t)(tileM + r0) * E_SZ + g0 * 8;
        Xf1 = X + (size_t)(tileM + r1) * E_SZ + g1 * 8;
    } else {
        const ushort_t* X = (const ushort_t*)Xv;
        Xb0 = X + (size_t)(tileM + r0) * E_SZ + g0 * 8;
        Xb1 = X + (size_t)(tileM + r1) * E_SZ + g1 * 8;
    }

    for (int k0 = 0; k0 < E_SZ; k0 += 32) {
        if constexpr (XF32) {
            float4a u0 = *(const float4a*)(Xf0 + k0);
            float4a u1 = *(const float4a*)(Xf0 + k0 + 4);
            float4a u2 = *(const float4a*)(Xf1 + k0);
            float4a u3 = *(const float4a*)(Xf1 + k0 + 4);
            uint4a w0 = (uint4a){pk_bf16(u0[0], u0[1]), pk_bf16(u0[2], u0[3]),
                                 pk_bf16(u1[0], u1[1]), pk_bf16(u1[2], u1[3])};
            uint4a w1 = (uint4a){pk_bf16(u2[0], u2[1]), pk_bf16(u2[2], u2[3]),
                                 pk_bf16(u3[0], u3[1]), pk_bf16(u3[2], u3[3])};
            *(uint4a*)&As[L0 * 8] = w0;
            *(uint4a*)&As[L1 * 8] = w1;
        } else {
            async_copy16(Xb0 + k0, &As[L0 * 8]);
            async_copy16(Xb1 + k0, &As[L1 * 8]);
        }
        async_copy16(Wa0 + k0, &Bs[L0 * 8]);
        async_copy16(Wa1 + k0, &Bs[L1 * 8]);
        __syncthreads();
        short8 a[4], b[4];
        for (int mt = 0; mt < 4; mt++)
            a[mt] = *(const short8*)&As[quad * 1024 + (wm + mt * 16 + l15) * 8];
        for (int nt = 0; nt < 4; nt++)
            b[nt] = *(const short8*)&Bs[quad * 1024 + (wn + nt * 16 + l15) * 8];
        for (int mt = 0; mt < 4; mt++)
            for (int nt = 0; nt < 4; nt++)
                acc[mt][nt] = __builtin_amdgcn_mfma_f32_16x16x32_bf16(
                    a[mt], b[nt], acc[mt][nt], 0, 0, 0);
        __syncthreads();
    }

    for (int nt = 0; nt < 4; nt++) {
        int n = tileN + wn + nt * 16 + l15;
        float bv = bias[n];
        for (int mt = 0; mt < 4; mt++) {
            for (int r = 0; r < 4; r++) {
                int m = tileM + wm + mt * 16 + quad * 4 + r;
                float v = acc[mt][nt][r] + bv;
                if constexpr (OUTF32) {
                    ((float*)Yv)[(size_t)m * E_SZ + n] = v;
                } else {
                    ushort_t* Y = (ushort_t*)Yv;
                    if (mode == 0) {
                        Y[(size_t)m * E_SZ + n] = f2bf(v);
                    } else {
                        int bb = m >> 11, s = m & 2047;
                        Y[((size_t)(bb * E_SZ + n)) * S_SZ + s] = f2bf(v);
                    }
                }
            }
        }
    }
}

// ---- kernel 3: flash attention (all operands bf16, ws-resident) ----
// Q,K in [B,S,E]. V in [B,E,S] (transposed). Block: 128 q rows per (b,h),
// 4 waves x 32 q rows. S^T = K.Q^T (C-layout row=kidx, col=q); softmax in
// exp2 domain (scale folded into one FMA); P^T packed to bf16 via
// v_perm_b32 and round-tripped through XOR-swizzled LDS; O^T = V^T.P^T.
// Swizzle: phys(r,c) = r*128 + ((c>>3)^(r&7))*8 + (c&7)  -> b128 reads
// conflict-free, b64 writes max 4-way.
__global__ __launch_bounds__(256) void attn(
    const ushort_t* __restrict__ Q, const ushort_t* __restrict__ K,
    const ushort_t* __restrict__ V, ushort_t* __restrict__ ctx)
{
    // PQ: Qs [8][128][8] (8192) at kt==0, then Ps swizzled [128][128] (16384)
    __shared__ __align__(16) ushort_t smem[32768];   // 64 KB
    ushort_t* PQ = smem;
    ushort_t* Ks = smem + 16384;         // [g(8)][row(128)][8]
    ushort_t* Vt = smem + 24576;         // swizzled [d(64)][c(128)]

    const int tid = threadIdx.x;
    const int lane = tid & 63;
    const int quad = lane >> 4;
    const int l15 = lane & 15;
    const int wid = tid >> 6;
    const int qt = blockIdx.x;              // 0..15
    const int bh = blockIdx.y;              // 0..63
    const int b = bh >> 4, h = bh & 15;
    const int s0 = qt * 128;
    const int wq = wid * 32;
    const float CE = 0.18033688011f;        // 0.125 * log2(e)

    // stage Q once (completion covered by first in-loop barrier)
    for (int p = 0; p < 4; p++) {
        int L = p * 256 + tid;
        int g = L >> 7, r = L & 127;
        const ushort_t* src = Q + ((size_t)(b * S_SZ + s0 + r)) * E_SZ + h * HD_SZ + g * 8;
        async_copy16(src, &PQ[L * 8]);
    }

    float4a st[8][2];       // S^T acc: mt over kidx(8 x16), nt over q(2 x16)
    float4a o[4][2];        // O^T acc: mt over d(4 x16), nt over q(2 x16)
    for (int mt = 0; mt < 4; mt++)
        for (int nt = 0; nt < 2; nt++)
            o[mt][nt] = (float4a){0.f, 0.f, 0.f, 0.f};
    float mrow[2] = {-1e30f, -1e30f};   // raw-score units
    float lrow[2] = {0.f, 0.f};
    short8 qf[2][2];

    for (int kt = 0; kt < 16; kt++) {
        // stage K tile (async, lane-consecutive 16B)
        for (int p = 0; p < 4; p++) {
            int L = p * 256 + tid;
            int g = L >> 7, r = L & 127;
            const ushort_t* src = K + ((size_t)(b * S_SZ + kt * 128 + r)) * E_SZ + h * HD_SZ + g * 8;
            async_copy16(src, &Ks[L * 8]);
        }
        // stage V^T tile (swizzled rows of 128)
        for (int p = 0; p < 4; p++) {
            int c = p * 256 + tid;
            int d = c >> 4, cc = c & 15;
            const ushort_t* src = V + ((size_t)(b * E_SZ + h * HD_SZ + d)) * S_SZ + kt * 128 + cc * 8;
            short8 val = *(const short8*)src;
            *(short8*)&Vt[d * 128 + ((cc ^ (d & 7)) << 3)] = val;
        }
        __syncthreads();
        if (kt == 0) {
            for (int ks = 0; ks < 2; ks++)
                for (int nt = 0; nt < 2; nt++)
                    qf[ks][nt] = *(const short8*)&PQ[(ks * 4 + quad) * 1024 + (wq + nt * 16 + l15) * 8];
            __syncthreads();   // Ps writes below alias Qs; wait for all qf loads
        }

        // S^T[kidx][q] = sum_d K[kidx][d] * Q[q][d]
        for (int mt = 0; mt < 8; mt++)
            for (int nt = 0; nt < 2; nt++)
                st[mt][nt] = (float4a){0.f, 0.f, 0.f, 0.f};
        for (int ks = 0; ks < 2; ks++) {
            for (int mt = 0; mt < 8; mt++) {
                short8 kf = *(const short8*)&Ks[(ks * 4 + quad) * 1024 + (mt * 16 + l15) * 8];
                for (int nt = 0; nt < 2; nt++)
                    st[mt][nt] = __builtin_amdgcn_mfma_f32_16x16x32_bf16(
                        kf, qf[ks][nt], st[mt][nt], 0, 0, 0);
            }
        }

        // online softmax on raw scores; exp via exp2(st*CE - m*CE)
        float rmax[2] = {-1e30f, -1e30f};
        for (int mt = 0; mt < 8; mt++)
            for (int nt = 0; nt < 2; nt++)
                for (int r = 0; r < 4; r++)
                    rmax[nt] = fmaxf(rmax[nt], st[mt][nt][r]);
        for (int nt = 0; nt < 2; nt++) {
            rmax[nt] = fmaxf(rmax[nt], __shfl_xor(rmax[nt], 16));
            rmax[nt] = fmaxf(rmax[nt], __shfl_xor(rmax[nt], 32));
        }
        float alpha[2], mc[2], rsum[2] = {0.f, 0.f};
        for (int nt = 0; nt < 2; nt++) {
            float mn = fmaxf(mrow[nt], rmax[nt]);
            alpha[nt] = EXP2F((mrow[nt] - mn) * CE);
            mrow[nt] = mn;
            mc[nt] = mn * CE;
        }
        // exp, row-sum, perm-pack to bf16, swizzled LDS write (b64).
        // Each wave touches only its own q rows -> no barrier needed.
        for (int mt = 0; mt < 8; mt++)
            for (int nt = 0; nt < 2; nt++) {
                float e0 = EXP2F(fmaf(st[mt][nt][0], CE, -mc[nt]));
                float e1 = EXP2F(fmaf(st[mt][nt][1], CE, -mc[nt]));
                float e2 = EXP2F(fmaf(st[mt][nt][2], CE, -mc[nt]));
                float e3 = EXP2F(fmaf(st[mt][nt][3], CE, -mc[nt]));
                rsum[nt] += (e0 + e1) + (e2 + e3);
                uint2a pp = (uint2a){pk_bf16(e0, e1), pk_bf16(e2, e3)};
                int row = wq + nt * 16 + l15;
                // element col = mt*16 + quad*4 -> grp = 2mt + (quad>>1)
                *(uint2a*)&PQ[row * 128 + (((2 * mt + (quad >> 1)) ^ (row & 7)) << 3) + (quad & 1) * 4] = pp;
            }
        for (int nt = 0; nt < 2; nt++) {
            rsum[nt] += __shfl_xor(rsum[nt], 16);
            rsum[nt] += __shfl_xor(rsum[nt], 32);
            lrow[nt] = lrow[nt] * alpha[nt] + rsum[nt];
        }
        for (int mt = 0; mt < 4; mt++)
            for (int nt = 0; nt < 2; nt++)
                for (int r = 0; r < 4; r++)
                    o[mt][nt][r] *= alpha[nt];

        // O^T[d][q] += sum_kidx V^T[d][kidx] * P^T[kidx][q]  (16x16x32)
        for (int kk = 0; kk < 4; kk++) {
            int swz = ((kk * 4 + quad) ^ (l15 & 7)) << 3;   // row&7 == l15&7 for all rows used
            short8 a[4], pb[2];
            for (int mt = 0; mt < 4; mt++)
                a[mt] = *(const short8*)&Vt[(mt * 16 + l15) * 128 + swz];
            for (int nt = 0; nt < 2; nt++)
                pb[nt] = *(const short8*)&PQ[(wq + nt * 16 + l15) * 128 + swz];
            for (int mt = 0; mt < 4; mt++)
                for (int nt = 0; nt < 2; nt++)
                    o[mt][nt] = __builtin_amdgcn_mfma_f32_16x16x32_bf16(
                        a[mt], pb[nt], o[mt][nt], 0, 0, 0);
        }
        __syncthreads();
    }

    // epilogue: ctx[b, s, h*64+d] = O^T[d][q] / l[q]   (8B packed stores)
    for (int nt = 0; nt < 2; nt++) {
        float inv = 1.f / lrow[nt];
        int s = s0 + wq + nt * 16 + l15;
        size_t base = ((size_t)(b * S_SZ + s)) * E_SZ + h * HD_SZ;
        for (int mt = 0; mt < 4; mt++) {
            int d = mt * 16 + quad * 4;
            uint2a w = (uint2a){pk_bf16(o[mt][nt][0] * inv, o[mt][nt][1] * inv),
                                pk_bf16(o[mt][nt][2] * inv, o[mt][nt][3] * inv)};
            *(uint2a*)&ctx[base + d] = w;
        }
    }
}

extern "C" void kernel_launch(void* const* d_in, const int* in_sizes, int n_in,
                              void* d_out, int out_size, void* d_ws, size_t ws_size,
                              hipStream_t stream) {
    // Inputs fp32 per the reference; OUTPUT fp32 per the reference.
    const float* q_in = (const float*)d_in[0];
    const float* k_in = (const float*)d_in[1];
    const float* v_in = (const float*)d_in[2];
    const float* Wq = (const float*)d_in[3];
    const float* bq = (const float*)d_in[4];
    const float* Wk = (const float*)d_in[5];
    const float* bk = (const float*)d_in[6];
    const float* Wv = (const float*)d_in[7];
    const float* bv = (const float*)d_in[8];
    const float* Wo = (const float*)d_in[9];
    const float* bo = (const float*)d_in[10];

    ushort_t* ws = (ushort_t*)d_ws;
    const size_t WMAT = (size_t)E_SZ * E_SZ;           // 1M elements
    const size_t TEN = (size_t)B_SZ * S_SZ * E_SZ;     // 8M elements
    ushort_t* Wt = ws;                 // 4 transposed bf16 weight matrices
    ushort_t* qp = ws + 4 * WMAT;
    ushort_t* kp = qp + TEN;
    ushort_t* vp = kp + TEN;           // stored [B, E, S]
    ushort_t* cx = vp + TEN;

    transpose4<<<dim3(32, 32, 4), dim3(32, 8), 0, stream>>>(Wq, Wk, Wv, Wo, Wt);
    gemm_bt_bias<true, false><<<dim3(8, 64), 256, 0, stream>>>(q_in, Wt, bq, qp, 0);
    gemm_bt_bias<true, false><<<dim3(8, 64), 256, 0, stream>>>(k_in, Wt + WMAT, bk, kp, 0);
    gemm_bt_bias<true, false><<<dim3(8, 64), 256, 0, stream>>>(v_in, Wt + 2 * WMAT, bv, vp, 1);
    attn<<<dim3(16, 64), 256, 0, stream>>>(qp, kp, vp, cx);
    gemm_bt_bias<false, true><<<dim3(8, 64), 256, 0, stream>>>(cx, Wt + 3 * WMAT, bo, d_out, 0);
}